// Round 1
// baseline (27403.482 us; speedup 1.0000x reference)
//
#include <hip/hip_runtime.h>
#include <math.h>

#define Bsz 512
#define Tsz 128
#define Dsz 256
#define Lsz 3
#define CHs 128
#define CSs 10
#define Hsz 384      // L*CH
#define Gsz 1542     // 4H+2L
#define HSz 64       // H/6
#define KP  656      // padded K for XO gemm (>= 641, multiple of 16)
#define KC  3840     // H*CS, conv GEMM K
#define KSPLIT 4
#define KCHUNK 960   // KC / KSPLIT

// ---------------- ws layout (floats) ----------------
// [bufh CS*B*H][bufd CS*B][h B*H][c B*H]  <- zeroed each call
// [wc G*KP][bc G][xo B*G][aconv B*KC][theme B*H][cp KSPLIT*B*H]
#define O_BUFH 0
#define N_BUFH (CSs*Bsz*Hsz)                 // 1,966,080
#define O_BUFD (O_BUFH + N_BUFH)
#define N_BUFD (CSs*Bsz)                     // 5,120
#define O_H    (O_BUFD + N_BUFD)
#define O_C    (O_H + Bsz*Hsz)
#define ZERO_N (O_C + Bsz*Hsz)               // 2,364,416
#define O_WC   ZERO_N
#define O_BC   (O_WC + Gsz*KP)
#define O_XO   (O_BC + Gsz)
#define O_AC   (O_XO + Bsz*Gsz)
#define O_TH   (O_AC + Bsz*KC)
#define O_CP   (O_TH + Bsz*Hsz)

__global__ __launch_bounds__(256) void zero_k(float* __restrict__ p, int n) {
    int i = blockIdx.x * 256 + threadIdx.x;
    if (i < n) p[i] = 0.f;
}

__global__ __launch_bounds__(256) void build_wc(const float* __restrict__ kW,
                                                const float* __restrict__ kb,
                                                const float* __restrict__ rW,
                                                const float* __restrict__ rb,
                                                float* __restrict__ wc,
                                                float* __restrict__ bc) {
    int idx = blockIdx.x * 256 + threadIdx.x;
    if (idx < Gsz * KP) {
        int g = idx / KP, k = idx % KP;
        float v;
        if (k < Dsz)            v = kW[g * (Dsz + 1) + k];
        else if (k < Dsz + Hsz) v = rW[g * (Hsz + 1) + (k - Dsz)];
        else if (k == Dsz + Hsz) v = kW[g * (Dsz + 1) + Dsz] + rW[g * (Hsz + 1) + Hsz];
        else                    v = 0.f;
        wc[idx] = v;
    }
    if (idx < Gsz) bc[idx] = kb[idx] + rb[idx];
}

// xo[b,g] = sum_k A[b,k]*Wc[g,k] + bc[g]
// A[b, 0:256]=x[b,t,:], A[b,256:640]=h[b,:], A[b,640]=time[b,t], rest 0
__global__ __launch_bounds__(256) void gemm_xo(const float* __restrict__ x,
                                               const float* __restrict__ tme,
                                               const float* __restrict__ wc,
                                               const float* __restrict__ bc,
                                               const float* __restrict__ h,
                                               float* __restrict__ xo, int t) {
    __shared__ float As[16][64];
    __shared__ float Bs[16][64];
    int tid = threadIdx.x;
    int tx = tid & 15, ty = tid >> 4;
    int gb = blockIdx.x * 64;   // N (g) offset
    int bb = blockIdx.y * 64;   // M (b) offset
    float acc[4][4] = {{0.f}};
    for (int k0 = 0; k0 < KP; k0 += 16) {
        #pragma unroll
        for (int i = 0; i < 4; ++i) {
            int e = tid + i * 256;
            int m = e & 63, kk = e >> 6;
            int k = k0 + kk;
            int row = bb + m;
            float av;
            if (k < Dsz)             av = x[((size_t)row * Tsz + t) * Dsz + k];
            else if (k < Dsz + Hsz)  av = h[row * Hsz + (k - Dsz)];
            else if (k == Dsz + Hsz) av = tme[row * Tsz + t];
            else                     av = 0.f;
            As[kk][m] = av;
            int g = gb + m;
            Bs[kk][m] = (g < Gsz) ? wc[(size_t)g * KP + k] : 0.f;
        }
        __syncthreads();
        #pragma unroll
        for (int kk = 0; kk < 16; ++kk) {
            float4 a4 = *reinterpret_cast<const float4*>(&As[kk][ty * 4]);
            float4 b4 = *reinterpret_cast<const float4*>(&Bs[kk][tx * 4]);
            float a[4] = {a4.x, a4.y, a4.z, a4.w};
            float bv[4] = {b4.x, b4.y, b4.z, b4.w};
            #pragma unroll
            for (int i = 0; i < 4; ++i)
                #pragma unroll
                for (int j = 0; j < 4; ++j)
                    acc[i][j] += a[i] * bv[j];
        }
        __syncthreads();
    }
    #pragma unroll
    for (int i = 0; i < 4; ++i) {
        int row = bb + ty * 4 + i;
        #pragma unroll
        for (int j = 0; j < 4; ++j) {
            int g = gb + tx * 4 + j;
            if (g < Gsz) xo[(size_t)row * Gsz + g] = acc[i][j] + bc[g];
        }
    }
}

__device__ __forceinline__ float sigm(float v) { return 1.f / (1.f + expf(-v)); }

// one block per batch row b; 384 threads
__global__ __launch_bounds__(384) void cell(const float* __restrict__ xo,
                                            float* __restrict__ h,
                                            float* __restrict__ c,
                                            float* __restrict__ bufh,
                                            float* __restrict__ bufd,
                                            const float* __restrict__ sW,
                                            const float* __restrict__ sb,
                                            const float* __restrict__ rsW,
                                            const float* __restrict__ rsb,
                                            float* __restrict__ aconv,
                                            float* __restrict__ theme,
                                            float* __restrict__ dist_out, int t) {
    __shared__ float s_fm[Lsz], s_im[Lsz];
    __shared__ float s_hn[Hsz], s_thm[Hsz];
    __shared__ float s_ld[CSs];
    __shared__ float s_th1[HSz];
    __shared__ float s_part[6][HSz];
    __shared__ float s_cd;

    int b = blockIdx.x;
    int tid = threadIdx.x;
    const float* xr = xo + (size_t)b * Gsz;

    if (tid == 0) {
        // fm = cumax_l2r(xo[:3]); im = cumax_r2l(xo[3:6])
        float z0 = xr[0], z1 = xr[1], z2 = xr[2];
        float m = fmaxf(z0, fmaxf(z1, z2));
        float e0 = expf(z0 - m), e1 = expf(z1 - m), e2 = expf(z2 - m);
        float inv = 1.f / (e0 + e1 + e2);
        float p0 = e0 * inv, p1 = e1 * inv;
        s_fm[0] = p0; s_fm[1] = p0 + p1; s_fm[2] = 1.f;
        float w0 = xr[3], w1 = xr[4], w2 = xr[5];
        float mw = fmaxf(w0, fmaxf(w1, w2));
        float f0 = expf(w0 - mw), f1 = expf(w1 - mw), f2 = expf(w2 - mw);
        float invw = 1.f / (f0 + f1 + f2);
        float q1 = f1 * invw, q2 = f2 * invw;
        s_im[0] = 1.f; s_im[1] = q1 + q2; s_im[2] = q2;
        float cd = 1.f - (s_fm[0] + s_fm[1] + s_fm[2]) * (1.f / 3.f);
        s_cd = cd;
        bufd[(t % CSs) * Bsz + b] = cd;
        dist_out[(size_t)t * Bsz + b] = cd;
    }
    __syncthreads();

    {   // gates + cell update; tid = l*128 + ch
        int l = tid >> 7;
        float fm = s_fm[l], im = s_im[l];
        float fg = sigm(xr[2 * Lsz + tid]);
        float ig = sigm(xr[2 * Lsz + Hsz + tid]);
        float og = sigm(xr[2 * Lsz + 2 * Hsz + tid]);
        float ci = tanhf(xr[2 * Lsz + 3 * Hsz + tid]);
        float cl = c[(size_t)b * Hsz + tid];
        float ov = fm * im;
        float cn = ov * (fg * cl + ig * ci) + (fm - ov) * cl + (im - ov) * ci;
        float hn = og * tanhf(cn);
        c[(size_t)b * Hsz + tid] = cn;
        h[(size_t)b * Hsz + tid] = hn;
        s_hn[tid] = hn;
        bufh[((size_t)(t % CSs) * Bsz + b) * Hsz + tid] = hn;
    }
    __syncthreads();

    if (tid == 0) {
        // local_dis = softmax(cumsum over window, oldest->newest)
        float vals[CSs];
        float cum = 0.f;
        #pragma unroll
        for (int j = 0; j < CSs; ++j) {
            int slot = (t + 1 + j) % CSs;
            float d = (j == CSs - 1) ? s_cd : bufd[slot * Bsz + b];
            cum += d;
            vals[j] = cum;
        }
        float mx = vals[0];
        #pragma unroll
        for (int j = 1; j < CSs; ++j) mx = fmaxf(mx, vals[j]);
        float sum = 0.f;
        #pragma unroll
        for (int j = 0; j < CSs; ++j) { vals[j] = expf(vals[j] - mx); sum += vals[j]; }
        float invs = 1.f / sum;
        #pragma unroll
        for (int j = 0; j < CSs; ++j) s_ld[j] = vals[j] * invs;
    }
    __syncthreads();

    {   // A_conv row + theme-mean; tid = channel
        float acc = 0.f;
        float* arow = aconv + (size_t)b * KC + (size_t)tid * CSs;
        #pragma unroll
        for (int j = 0; j < CSs; ++j) {
            int slot = (t + 1 + j) % CSs;
            float v = (j == CSs - 1) ? s_hn[tid]
                                     : bufh[((size_t)slot * Bsz + b) * Hsz + tid];
            float av = v * s_ld[j];
            arow[j] = av;
            acc += av;
        }
        s_thm[tid] = acc * 0.1f;
    }
    __syncthreads();

    {   // th1 partials: hs = tid&63, chunk = tid>>6 (0..5)
        int hs = tid & 63, ck = tid >> 6;
        const float* swr = sW + (size_t)hs * Hsz + ck * 64;
        const float* tm = s_thm + ck * 64;
        float p = 0.f;
        #pragma unroll
        for (int i = 0; i < 64; ++i) p += tm[i] * swr[i];
        s_part[ck][hs] = p;
    }
    __syncthreads();
    if (tid < HSz) {
        float v = sb[tid];
        #pragma unroll
        for (int ck = 0; ck < 6; ++ck) v += s_part[ck][tid];
        s_th1[tid] = fmaxf(v, 0.f);
    }
    __syncthreads();
    {   // theme[o] = sigmoid(th1 @ rsW[o,:] + rsb[o]); tid = o
        const float* rr = rsW + (size_t)tid * HSz;
        float v = rsb[tid];
        #pragma unroll
        for (int hs = 0; hs < HSz; ++hs) v += s_th1[hs] * rr[hs];
        theme[(size_t)b * Hsz + tid] = sigm(v);
    }
}

// conv partials: cp[z][b][o] = sum_{k in chunk z} aconv[b,k] * cW[o,k]
__global__ __launch_bounds__(256) void gemm_conv(const float* __restrict__ A,
                                                 const float* __restrict__ Bm,
                                                 float* __restrict__ cp) {
    __shared__ float As[16][64];
    __shared__ float Bs[16][64];
    int tid = threadIdx.x;
    int tx = tid & 15, ty = tid >> 4;
    int bb = blockIdx.x * 64;   // M (b)
    int ob = blockIdx.y * 64;   // N (o)
    int z = blockIdx.z;
    int kstart = z * KCHUNK;
    float acc[4][4] = {{0.f}};
    for (int k0 = 0; k0 < KCHUNK; k0 += 16) {
        #pragma unroll
        for (int i = 0; i < 4; ++i) {
            int e = tid + i * 256;
            int m = e & 63, kk = e >> 6;
            int k = kstart + k0 + kk;
            As[kk][m] = A[(size_t)(bb + m) * KC + k];
            Bs[kk][m] = Bm[(size_t)(ob + m) * KC + k];
        }
        __syncthreads();
        #pragma unroll
        for (int kk = 0; kk < 16; ++kk) {
            float4 a4 = *reinterpret_cast<const float4*>(&As[kk][ty * 4]);
            float4 b4 = *reinterpret_cast<const float4*>(&Bs[kk][tx * 4]);
            float a[4] = {a4.x, a4.y, a4.z, a4.w};
            float bv[4] = {b4.x, b4.y, b4.z, b4.w};
            #pragma unroll
            for (int i = 0; i < 4; ++i)
                #pragma unroll
                for (int j = 0; j < 4; ++j)
                    acc[i][j] += a[i] * bv[j];
        }
        __syncthreads();
    }
    #pragma unroll
    for (int i = 0; i < 4; ++i) {
        int row = bb + ty * 4 + i;
        #pragma unroll
        for (int j = 0; j < 4; ++j) {
            int col = ob + tx * 4 + j;
            cp[((size_t)z * Bsz + row) * Hsz + col] = acc[i][j];
        }
    }
}

__global__ __launch_bounds__(256) void epilogue(const float* __restrict__ cp,
                                                const float* __restrict__ theme,
                                                const float* __restrict__ h,
                                                const float* __restrict__ cb,
                                                float* __restrict__ out_seq,
                                                float* __restrict__ out_last, int t) {
    int idx = blockIdx.x * 256 + threadIdx.x;
    if (idx >= Bsz * Hsz) return;
    int b = idx / Hsz, o = idx % Hsz;
    float conv = cb[o];
    #pragma unroll
    for (int z = 0; z < KSPLIT; ++z) conv += cp[(size_t)z * Bsz * Hsz + idx];
    float val = theme[idx] * conv + h[idx];
    out_seq[((size_t)b * Tsz + t) * Hsz + o] = val;
    if (t == Tsz - 1) out_last[idx] = val;
}

extern "C" void kernel_launch(void* const* d_in, const int* in_sizes, int n_in,
                              void* d_out, int out_size, void* d_ws, size_t ws_size,
                              hipStream_t stream) {
    const float* x   = (const float*)d_in[0];
    const float* tme = (const float*)d_in[1];
    const float* kW  = (const float*)d_in[2];
    const float* kb  = (const float*)d_in[3];
    const float* rW  = (const float*)d_in[4];
    const float* rb  = (const float*)d_in[5];
    const float* sW  = (const float*)d_in[6];
    const float* sb  = (const float*)d_in[7];
    const float* rsW = (const float*)d_in[8];
    const float* rsb = (const float*)d_in[9];
    const float* cW  = (const float*)d_in[10];
    const float* cb  = (const float*)d_in[11];

    float* ws = (float*)d_ws;
    float* bufh  = ws + O_BUFH;
    float* bufd  = ws + O_BUFD;
    float* h     = ws + O_H;
    float* c     = ws + O_C;
    float* wc    = ws + O_WC;
    float* bc    = ws + O_BC;
    float* xo    = ws + O_XO;
    float* aconv = ws + O_AC;
    float* theme = ws + O_TH;
    float* cp    = ws + O_CP;

    float* out_last = (float*)d_out;
    float* out_seq  = out_last + (size_t)Bsz * Hsz;
    float* out_dist = out_seq + (size_t)Bsz * Tsz * Hsz;

    zero_k<<<(ZERO_N + 255) / 256, 256, 0, stream>>>(ws, ZERO_N);
    build_wc<<<(Gsz * KP + 255) / 256, 256, 0, stream>>>(kW, kb, rW, rb, wc, bc);

    for (int t = 0; t < Tsz; ++t) {
        gemm_xo<<<dim3((Gsz + 63) / 64, Bsz / 64), 256, 0, stream>>>(x, tme, wc, bc, h, xo, t);
        cell<<<Bsz, 384, 0, stream>>>(xo, h, c, bufh, bufd, sW, sb, rsW, rsb,
                                      aconv, theme, out_dist, t);
        gemm_conv<<<dim3(Bsz / 64, Hsz / 64, KSPLIT), 256, 0, stream>>>(aconv, cW, cp);
        epilogue<<<(Bsz * Hsz + 255) / 256, 256, 0, stream>>>(cp, theme, h, cb,
                                                              out_seq, out_last, t);
    }
}

// Round 2
// 6787.214 us; speedup vs baseline: 4.0375x; 4.0375x over previous
//
#include <hip/hip_runtime.h>
#include <math.h>

typedef unsigned short u16;
typedef __attribute__((ext_vector_type(8))) short bf16x8;
typedef __attribute__((ext_vector_type(4))) float f32x4;

#define Bsz 512
#define Tsz 128
#define Dsz 256
#define Lsz 3
#define CHs 128
#define CSs 10
#define Hsz 384      // L*CH
#define Gsz 1542     // 4H+2L
#define HSz 64       // H/6
#define Gp  1568     // padded G (49*32)
#define KA  672      // padded K for rxo: [0,256)=x, [256,640)=h, [640]=time, rest 0
#define KC  3840     // H*CS
#define CKZ 8        // conv K-split
#define CKCH (KC/CKZ)

// ---------------- ws layout (byte offsets) ----------------
#define ALIGN256(x) (((x) + 255) & ~(size_t)255)
constexpr size_t O_BUFH = 0;                                        // f32 CS*B*H
constexpr size_t O_BUFD = O_BUFH + sizeof(float)*CSs*Bsz*Hsz;       // f32 CS*B
constexpr size_t O_HF   = O_BUFD + sizeof(float)*CSs*Bsz;           // f32 B*H
constexpr size_t O_CF   = O_HF   + sizeof(float)*Bsz*Hsz;           // f32 B*H
constexpr size_t O_HHI  = O_CF   + sizeof(float)*Bsz*Hsz;           // u16 B*H
constexpr size_t O_HLO  = O_HHI  + 2ull*Bsz*Hsz;                    // u16 B*H
constexpr size_t ZERO_END = O_HLO + 2ull*Bsz*Hsz;                   // zeroed each call
constexpr size_t O_WHI  = ZERO_END;                                 // u16 Gp*KA
constexpr size_t O_WLO  = O_WHI + 2ull*Gp*KA;
constexpr size_t O_BC   = O_WLO + 2ull*Gp*KA;                       // f32 Gsz
constexpr size_t O_XHI  = ALIGN256(O_BC + 4ull*Gsz);                // u16 B*T*D
constexpr size_t O_XLO  = O_XHI + 2ull*Bsz*Tsz*Dsz;
constexpr size_t O_THI  = O_XLO + 2ull*Bsz*Tsz*Dsz;                 // u16 B*T
constexpr size_t O_TLO  = O_THI + 2ull*Bsz*Tsz;
constexpr size_t O_XOP  = O_TLO + 2ull*Bsz*Tsz;                     // f32 2*B*Gp
constexpr size_t O_ACV  = O_XOP + 4ull*2*Bsz*Gp;                    // u16 B*KC
constexpr size_t O_THM  = O_ACV + 2ull*Bsz*KC;                      // f32 B*H
constexpr size_t O_CP   = O_THM + 4ull*Bsz*Hsz;                     // f32 CKZ*B*H
constexpr size_t O_CWB  = O_CP  + 4ull*CKZ*Bsz*Hsz;                 // u16 H*KC

__device__ __forceinline__ u16 f2bf(float f) {
    unsigned u = __float_as_uint(f);
    unsigned r = (u + 0x7FFFu + ((u >> 16) & 1u)) >> 16;
    return (u16)r;
}
__device__ __forceinline__ float bf2f(u16 v) {
    return __uint_as_float(((unsigned)v) << 16);
}
__device__ __forceinline__ float sigm(float v) { return 1.f / (1.f + expf(-v)); }

__global__ __launch_bounds__(256) void zero4(float4* __restrict__ p, int n4) {
    int i = blockIdx.x * 256 + threadIdx.x;
    if (i < n4) p[i] = make_float4(0.f, 0.f, 0.f, 0.f);
}

__global__ __launch_bounds__(256) void split_f32(const float* __restrict__ src,
                                                 u16* __restrict__ hi,
                                                 u16* __restrict__ lo, int n) {
    int i = blockIdx.x * 256 + threadIdx.x;
    if (i < n) {
        float v = src[i];
        u16 a = f2bf(v);
        hi[i] = a;
        lo[i] = f2bf(v - bf2f(a));
    }
}

__global__ __launch_bounds__(256) void cvt_bf16(const float* __restrict__ src,
                                                u16* __restrict__ dst, int n) {
    int i = blockIdx.x * 256 + threadIdx.x;
    if (i < n) dst[i] = f2bf(src[i]);
}

__global__ __launch_bounds__(256) void build_w(const float* __restrict__ kW,
                                               const float* __restrict__ kb,
                                               const float* __restrict__ rW,
                                               const float* __restrict__ rb,
                                               u16* __restrict__ whi,
                                               u16* __restrict__ wlo,
                                               float* __restrict__ bc) {
    int idx = blockIdx.x * 256 + threadIdx.x;
    if (idx < Gp * KA) {
        int g = idx / KA, k = idx % KA;
        float v = 0.f;
        if (g < Gsz) {
            if (k < Dsz)              v = kW[g * (Dsz + 1) + k];
            else if (k < Dsz + Hsz)   v = rW[g * (Hsz + 1) + (k - Dsz)];
            else if (k == Dsz + Hsz)  v = kW[g * (Dsz + 1) + Dsz] + rW[g * (Hsz + 1) + Hsz];
        }
        u16 hi = f2bf(v);
        whi[idx] = hi;
        wlo[idx] = f2bf(v - bf2f(hi));
    }
    if (idx < Gsz) bc[idx] = kb[idx] + rb[idx];
}

// xo partials: xop[kz][b][g] = sum_{k in half kz} A[b,k]*Wc[g,k]   (split-bf16, 3 MFMA terms)
__global__ __launch_bounds__(256) void gemm_rxo(const u16* __restrict__ xhi,
                                                const u16* __restrict__ xlo,
                                                const u16* __restrict__ thi,
                                                const u16* __restrict__ tlo,
                                                const u16* __restrict__ whi,
                                                const u16* __restrict__ wlo,
                                                const u16* __restrict__ hhi,
                                                const u16* __restrict__ hlo,
                                                float* __restrict__ xop, int t) {
    int lane = threadIdx.x & 63;
    int wave = threadIdx.x >> 6;
    int l15 = lane & 15, lk = lane >> 4;
    int mbase = blockIdx.x * 128 + wave * 32;
    int nbase = blockIdx.y * 32;
    int kz = blockIdx.z;

    f32x4 acc[2][2] = {};
    int kbeg = kz ? 352 : 0;
    int kend = kz ? KA : 352;
    for (int k0 = kbeg; k0 < kend; k0 += 32) {
        int k8 = k0 + lk * 8;
        bf16x8 ahi[2], alo[2], bhi[2], blo[2];
        #pragma unroll
        for (int mi = 0; mi < 2; ++mi) {
            int row = mbase + mi * 16 + l15;
            if (k8 < Dsz) {
                size_t off = ((size_t)row * Tsz + t) * Dsz + k8;
                ahi[mi] = *(const bf16x8*)(xhi + off);
                alo[mi] = *(const bf16x8*)(xlo + off);
            } else if (k8 < Dsz + Hsz) {
                size_t off = (size_t)row * Hsz + (k8 - Dsz);
                ahi[mi] = *(const bf16x8*)(hhi + off);
                alo[mi] = *(const bf16x8*)(hlo + off);
            } else {
                bf16x8 zh = {}; bf16x8 zl = {};
                if (k8 == Dsz + Hsz) {
                    zh[0] = (short)thi[row * Tsz + t];
                    zl[0] = (short)tlo[row * Tsz + t];
                }
                ahi[mi] = zh; alo[mi] = zl;
            }
        }
        #pragma unroll
        for (int ni = 0; ni < 2; ++ni) {
            size_t off = (size_t)(nbase + ni * 16 + l15) * KA + k8;
            bhi[ni] = *(const bf16x8*)(whi + off);
            blo[ni] = *(const bf16x8*)(wlo + off);
        }
        #pragma unroll
        for (int mi = 0; mi < 2; ++mi)
        #pragma unroll
        for (int ni = 0; ni < 2; ++ni) {
            acc[mi][ni] = __builtin_amdgcn_mfma_f32_16x16x32_bf16(ahi[mi], bhi[ni], acc[mi][ni], 0, 0, 0);
            acc[mi][ni] = __builtin_amdgcn_mfma_f32_16x16x32_bf16(ahi[mi], blo[ni], acc[mi][ni], 0, 0, 0);
            acc[mi][ni] = __builtin_amdgcn_mfma_f32_16x16x32_bf16(alo[mi], bhi[ni], acc[mi][ni], 0, 0, 0);
        }
    }
    float* outp = xop + (size_t)kz * Bsz * Gp;
    #pragma unroll
    for (int mi = 0; mi < 2; ++mi)
    #pragma unroll
    for (int ni = 0; ni < 2; ++ni) {
        int col = nbase + ni * 16 + l15;
        #pragma unroll
        for (int j = 0; j < 4; ++j) {
            int row = mbase + mi * 16 + lk * 4 + j;
            outp[(size_t)row * Gp + col] = acc[mi][ni][j];
        }
    }
}

// conv partials: cp[kz][b][o] = sum_{k in chunk} aconv[b,k]*cWb[o,k]  (bf16 MFMA)
__global__ __launch_bounds__(256) void gemm_conv(const u16* __restrict__ A,
                                                 const u16* __restrict__ Bw,
                                                 float* __restrict__ cp) {
    int lane = threadIdx.x & 63;
    int wave = threadIdx.x >> 6;
    int l15 = lane & 15, lk = lane >> 4;
    int mbase = blockIdx.x * 128 + wave * 32;
    int nbase = blockIdx.y * 32;
    int kz = blockIdx.z;
    f32x4 acc[2][2] = {};
    int kstart = kz * CKCH;
    for (int kk = 0; kk < CKCH; kk += 32) {
        int k8 = kstart + kk + lk * 8;
        bf16x8 a[2], b[2];
        #pragma unroll
        for (int mi = 0; mi < 2; ++mi)
            a[mi] = *(const bf16x8*)(A + (size_t)(mbase + mi * 16 + l15) * KC + k8);
        #pragma unroll
        for (int ni = 0; ni < 2; ++ni)
            b[ni] = *(const bf16x8*)(Bw + (size_t)(nbase + ni * 16 + l15) * KC + k8);
        #pragma unroll
        for (int mi = 0; mi < 2; ++mi)
        #pragma unroll
        for (int ni = 0; ni < 2; ++ni)
            acc[mi][ni] = __builtin_amdgcn_mfma_f32_16x16x32_bf16(a[mi], b[ni], acc[mi][ni], 0, 0, 0);
    }
    float* outp = cp + (size_t)kz * Bsz * Hsz;
    #pragma unroll
    for (int mi = 0; mi < 2; ++mi)
    #pragma unroll
    for (int ni = 0; ni < 2; ++ni) {
        int col = nbase + ni * 16 + l15;
        #pragma unroll
        for (int j = 0; j < 4; ++j) {
            int row = mbase + mi * 16 + lk * 4 + j;
            outp[(size_t)row * Hsz + col] = acc[mi][ni][j];
        }
    }
}

// one block per batch row; 384 threads. Also finishes step t-1's output.
__global__ __launch_bounds__(384) void cell(const float* __restrict__ xop,
                                            const float* __restrict__ bc,
                                            float* __restrict__ h,
                                            float* __restrict__ c,
                                            u16* __restrict__ hhi,
                                            u16* __restrict__ hlo,
                                            float* __restrict__ bufh,
                                            float* __restrict__ bufd,
                                            const float* __restrict__ sW,
                                            const float* __restrict__ sb,
                                            const float* __restrict__ rsW,
                                            const float* __restrict__ rsb,
                                            u16* __restrict__ aconv,
                                            float* theme,
                                            float* __restrict__ dist_out,
                                            const float* __restrict__ cp,
                                            const float* __restrict__ cb,
                                            float* __restrict__ out_seq, int t) {
    __shared__ float s_fm[Lsz], s_im[Lsz];
    __shared__ float s_hn[Hsz], s_thm[Hsz];
    __shared__ float s_ld[CSs];
    __shared__ float s_th1[HSz];
    __shared__ float s_part[6][HSz];
    __shared__ float s_cd;

    int b = blockIdx.x;
    int tid = threadIdx.x;
    const float* x0 = xop + (size_t)b * Gp;
    const float* x1 = xop + ((size_t)Bsz + b) * Gp;

    // ---- merged epilogue for step t-1 (reads theme/cp/h before overwrite) ----
    if (t > 0) {
        float convv = cb[tid];
        #pragma unroll
        for (int z = 0; z < CKZ; ++z)
            convv += cp[((size_t)z * Bsz + b) * Hsz + tid];
        float val = theme[(size_t)b * Hsz + tid] * convv + h[(size_t)b * Hsz + tid];
        out_seq[((size_t)b * Tsz + (t - 1)) * Hsz + tid] = val;
    }

    if (tid == 0) {
        float z0 = x0[0] + x1[0] + bc[0];
        float z1 = x0[1] + x1[1] + bc[1];
        float z2 = x0[2] + x1[2] + bc[2];
        float m = fmaxf(z0, fmaxf(z1, z2));
        float e0 = expf(z0 - m), e1 = expf(z1 - m), e2 = expf(z2 - m);
        float inv = 1.f / (e0 + e1 + e2);
        float p0 = e0 * inv, p1 = e1 * inv;
        s_fm[0] = p0; s_fm[1] = p0 + p1; s_fm[2] = 1.f;
        float w0 = x0[3] + x1[3] + bc[3];
        float w1 = x0[4] + x1[4] + bc[4];
        float w2 = x0[5] + x1[5] + bc[5];
        float mw = fmaxf(w0, fmaxf(w1, w2));
        float f0 = expf(w0 - mw), f1 = expf(w1 - mw), f2 = expf(w2 - mw);
        float invw = 1.f / (f0 + f1 + f2);
        float q1 = f1 * invw, q2 = f2 * invw;
        s_im[0] = 1.f; s_im[1] = q1 + q2; s_im[2] = q2;
        float cd = 1.f - (s_fm[0] + s_fm[1] + s_fm[2]) * (1.f / 3.f);
        s_cd = cd;
        bufd[(t % CSs) * Bsz + b] = cd;
        dist_out[(size_t)t * Bsz + b] = cd;
    }
    __syncthreads();

    {   // gates + cell update
        int l = tid >> 7;
        float fm = s_fm[l], im = s_im[l];
        int g0 = 2 * Lsz + tid;
        float fg = sigm(x0[g0] + x1[g0] + bc[g0]);
        float ig = sigm(x0[g0 + Hsz] + x1[g0 + Hsz] + bc[g0 + Hsz]);
        float og = sigm(x0[g0 + 2 * Hsz] + x1[g0 + 2 * Hsz] + bc[g0 + 2 * Hsz]);
        float ci = tanhf(x0[g0 + 3 * Hsz] + x1[g0 + 3 * Hsz] + bc[g0 + 3 * Hsz]);
        float cl = c[(size_t)b * Hsz + tid];
        float ov = fm * im;
        float cn = ov * (fg * cl + ig * ci) + (fm - ov) * cl + (im - ov) * ci;
        float hn = og * tanhf(cn);
        c[(size_t)b * Hsz + tid] = cn;
        h[(size_t)b * Hsz + tid] = hn;
        u16 hh = f2bf(hn);
        hhi[(size_t)b * Hsz + tid] = hh;
        hlo[(size_t)b * Hsz + tid] = f2bf(hn - bf2f(hh));
        s_hn[tid] = hn;
        bufh[((size_t)(t % CSs) * Bsz + b) * Hsz + tid] = hn;
    }
    __syncthreads();

    if (tid == 0) {
        float vals[CSs];
        float cum = 0.f;
        #pragma unroll
        for (int j = 0; j < CSs; ++j) {
            int slot = (t + 1 + j) % CSs;
            float d = (j == CSs - 1) ? s_cd : bufd[slot * Bsz + b];
            cum += d;
            vals[j] = cum;
        }
        float mx = vals[0];
        #pragma unroll
        for (int j = 1; j < CSs; ++j) mx = fmaxf(mx, vals[j]);
        float sum = 0.f;
        #pragma unroll
        for (int j = 0; j < CSs; ++j) { vals[j] = expf(vals[j] - mx); sum += vals[j]; }
        float invs = 1.f / sum;
        #pragma unroll
        for (int j = 0; j < CSs; ++j) s_ld[j] = vals[j] * invs;
    }
    __syncthreads();

    {   // aconv row (bf16) + theme-mean
        float acc = 0.f;
        u16* arow = aconv + (size_t)b * KC + (size_t)tid * CSs;
        #pragma unroll
        for (int j = 0; j < CSs; ++j) {
            int slot = (t + 1 + j) % CSs;
            float v = (j == CSs - 1) ? s_hn[tid]
                                     : bufh[((size_t)slot * Bsz + b) * Hsz + tid];
            float av = v * s_ld[j];
            arow[j] = f2bf(av);
            acc += av;
        }
        s_thm[tid] = acc * 0.1f;
    }
    __syncthreads();

    {   // theme MLP stage 1
        int hs = tid & 63, ck = tid >> 6;
        const float* swr = sW + (size_t)hs * Hsz + ck * 64;
        const float* tm = s_thm + ck * 64;
        float p = 0.f;
        #pragma unroll
        for (int i = 0; i < 64; ++i) p += tm[i] * swr[i];
        s_part[ck][hs] = p;
    }
    __syncthreads();
    if (tid < HSz) {
        float v = sb[tid];
        #pragma unroll
        for (int ck = 0; ck < 6; ++ck) v += s_part[ck][tid];
        s_th1[tid] = fmaxf(v, 0.f);
    }
    __syncthreads();
    {   // theme MLP stage 2
        const float* rr = rsW + (size_t)tid * HSz;
        float v = rsb[tid];
        #pragma unroll
        for (int hs = 0; hs < HSz; ++hs) v += s_th1[hs] * rr[hs];
        theme[(size_t)b * Hsz + tid] = sigm(v);
    }
}

__global__ __launch_bounds__(256) void epi_last(const float* __restrict__ cp,
                                                const float* __restrict__ theme,
                                                const float* __restrict__ h,
                                                const float* __restrict__ cb,
                                                float* __restrict__ out_seq,
                                                float* __restrict__ out_last) {
    int idx = blockIdx.x * 256 + threadIdx.x;
    if (idx >= Bsz * Hsz) return;
    int b = idx / Hsz, o = idx % Hsz;
    float convv = cb[o];
    #pragma unroll
    for (int z = 0; z < CKZ; ++z) convv += cp[(size_t)z * Bsz * Hsz + idx];
    float val = theme[idx] * convv + h[idx];
    out_seq[((size_t)b * Tsz + (Tsz - 1)) * Hsz + o] = val;
    out_last[idx] = val;
}

extern "C" void kernel_launch(void* const* d_in, const int* in_sizes, int n_in,
                              void* d_out, int out_size, void* d_ws, size_t ws_size,
                              hipStream_t stream) {
    const float* x   = (const float*)d_in[0];
    const float* tme = (const float*)d_in[1];
    const float* kW  = (const float*)d_in[2];
    const float* kb  = (const float*)d_in[3];
    const float* rW  = (const float*)d_in[4];
    const float* rb  = (const float*)d_in[5];
    const float* sW  = (const float*)d_in[6];
    const float* sb  = (const float*)d_in[7];
    const float* rsW = (const float*)d_in[8];
    const float* rsb = (const float*)d_in[9];
    const float* cW  = (const float*)d_in[10];
    const float* cb  = (const float*)d_in[11];

    char* ws = (char*)d_ws;
    float* bufh = (float*)(ws + O_BUFH);
    float* bufd = (float*)(ws + O_BUFD);
    float* hf   = (float*)(ws + O_HF);
    float* cf   = (float*)(ws + O_CF);
    u16*   hhi  = (u16*)(ws + O_HHI);
    u16*   hlo  = (u16*)(ws + O_HLO);
    u16*   whi  = (u16*)(ws + O_WHI);
    u16*   wlo  = (u16*)(ws + O_WLO);
    float* bc   = (float*)(ws + O_BC);
    u16*   xhi  = (u16*)(ws + O_XHI);
    u16*   xlo  = (u16*)(ws + O_XLO);
    u16*   thi  = (u16*)(ws + O_THI);
    u16*   tlo  = (u16*)(ws + O_TLO);
    float* xop  = (float*)(ws + O_XOP);
    u16*   acv  = (u16*)(ws + O_ACV);
    float* thm  = (float*)(ws + O_THM);
    float* cp   = (float*)(ws + O_CP);
    u16*   cwb  = (u16*)(ws + O_CWB);

    float* out_last = (float*)d_out;
    float* out_seq  = out_last + (size_t)Bsz * Hsz;
    float* out_dist = out_seq + (size_t)Bsz * Tsz * Hsz;

    zero4<<<(int)((ZERO_END / 16 + 255) / 256), 256, 0, stream>>>((float4*)ws, (int)(ZERO_END / 16));
    split_f32<<<(Bsz * Tsz * Dsz + 255) / 256, 256, 0, stream>>>(x, xhi, xlo, Bsz * Tsz * Dsz);
    split_f32<<<(Bsz * Tsz + 255) / 256, 256, 0, stream>>>(tme, thi, tlo, Bsz * Tsz);
    build_w<<<(Gp * KA + 255) / 256, 256, 0, stream>>>(kW, kb, rW, rb, whi, wlo, bc);
    cvt_bf16<<<(Hsz * KC + 255) / 256, 256, 0, stream>>>(cW, cwb, Hsz * KC);

    for (int t = 0; t < Tsz; ++t) {
        gemm_rxo<<<dim3(4, 49, 2), 256, 0, stream>>>(xhi, xlo, thi, tlo, whi, wlo,
                                                     hhi, hlo, xop, t);
        cell<<<Bsz, 384, 0, stream>>>(xop, bc, hf, cf, hhi, hlo, bufh, bufd,
                                      sW, sb, rsW, rsb, acv, thm, out_dist,
                                      cp, cb, out_seq, t);
        gemm_conv<<<dim3(4, 12, CKZ), 256, 0, stream>>>(acv, cwb, cp);
    }
    epi_last<<<(Bsz * Hsz + 255) / 256, 256, 0, stream>>>(cp, thm, hf, cb, out_seq, out_last);
}

// Round 4
// 5398.279 us; speedup vs baseline: 5.0763x; 1.2573x over previous
//
#include <hip/hip_runtime.h>
#include <math.h>

typedef unsigned short u16;
typedef __attribute__((ext_vector_type(8))) short bf16x8;
typedef __attribute__((ext_vector_type(4))) float f32x4;

#define Bsz 512
#define Tsz 128
#define Dsz 256
#define Lsz 3
#define CSs 10
#define Hsz 384      // L*CH
#define Gsz 1542     // 4H+2L
#define HSz 64       // H/6
#define Gp  1568     // padded G (98*16)
#define NTG 98       // Gp/16
#define KH  384      // h-part K
#define KTH 12       // KH/32
#define KX  256      // x-part K (time handled as rank-1 in cell)
#define KTX 8
#define KC  3840     // H*CS
#define KTC 120
#define CKZ 8        // conv K-split
#define CITER 15     // KTC/CKZ

// ---------------- ws layout (byte offsets) ----------------
// zero region first
constexpr size_t O_HPK  = 0;                                     // u16 32*12*2*512
constexpr size_t O_CF   = O_HPK + 2ull*32*KTH*2*512;             // f32 B*H
constexpr size_t O_BUFH = O_CF + 4ull*Bsz*Hsz;                   // u16 CS*B*H
constexpr size_t O_BUFD = O_BUFH + 2ull*CSs*Bsz*Hsz;             // f32 CS*B
constexpr size_t ZERO_END = O_BUFD + 4ull*CSs*Bsz;               // 5,525,504 (div by 16)
constexpr size_t O_WPK  = ZERO_END;                              // u16 98*12*2*512
constexpr size_t O_XWPK = O_WPK + 2ull*NTG*KTH*2*512;            // u16 98*8*2*512
constexpr size_t O_CPK  = O_XWPK + 2ull*NTG*KTX*2*512;           // u16 24*120*512
constexpr size_t O_BC   = O_CPK + 2ull*24*KTC*512;               // f32 Gsz
constexpr size_t O_WT   = O_BC + 4ull*Gsz;                       // f32 Gsz
constexpr size_t O_XW   = ((O_WT + 4ull*Gsz) + 255) & ~(size_t)255; // f32 2*B*Gp
constexpr size_t O_HW   = O_XW + 4ull*2*Bsz*Gp;                  // f32 B*Gp
constexpr size_t O_CP   = O_HW + 4ull*Bsz*Gp;                    // f32 CKZ*B*H
constexpr size_t O_APK  = O_CP + 4ull*CKZ*Bsz*Hsz;               // u16 32*120*512
constexpr size_t O_THM  = O_APK + 2ull*32*KTC*512;               // f32 B*H
constexpr size_t O_HF   = O_THM + 4ull*Bsz*Hsz;                  // f32 B*H
constexpr size_t O_XPK  = O_HF + 4ull*Bsz*Hsz;                   // u16 T*32*8*2*512 (67MB)
// end = O_XPK + 2*128*32*8*2*512 = ~101MB

__device__ __forceinline__ u16 f2bf(float f) {
    unsigned u = __float_as_uint(f);
    unsigned r = (u + 0x7FFFu + ((u >> 16) & 1u)) >> 16;
    return (u16)r;
}
__device__ __forceinline__ float bf2f(u16 v) {
    return __uint_as_float(((unsigned)v) << 16);
}
__device__ __forceinline__ float sigm(float v) { return 1.f / (1.f + expf(-v)); }

__global__ __launch_bounds__(256) void zero4(float4* __restrict__ p, int n4) {
    int i = blockIdx.x * 256 + threadIdx.x;
    if (i < n4) p[i] = make_float4(0.f, 0.f, 0.f, 0.f);
}

// pack rW-part (K=384) -> wpk, kW-part (K=256) -> xwpk, bc, wt
__global__ __launch_bounds__(256) void build_w(const float* __restrict__ kW,
                                               const float* __restrict__ kb,
                                               const float* __restrict__ rW,
                                               const float* __restrict__ rb,
                                               u16* __restrict__ wpk,
                                               u16* __restrict__ xwpk,
                                               float* __restrict__ bc,
                                               float* __restrict__ wt) {
    const int N1 = Gp * KH, N2 = Gp * KX;
    int idx = blockIdx.x * 256 + threadIdx.x;
    if (idx < N1) {
        int g = idx / KH, k = idx % KH;
        float v = (g < Gsz) ? rW[g * (Hsz + 1) + k] : 0.f;
        u16 hi = f2bf(v), lo = f2bf(v - bf2f(hi));
        int frag = ((g >> 4) * KTH + (k >> 5)) * 2;
        int pos = ((g & 15) | (((k >> 3) & 3) << 4)) * 8 + (k & 7);
        wpk[frag * 512 + pos] = hi;
        wpk[(frag + 1) * 512 + pos] = lo;
    } else if (idx < N1 + N2) {
        int i = idx - N1;
        int g = i / KX, k = i % KX;
        float v = (g < Gsz) ? kW[g * (Dsz + 1) + k] : 0.f;
        u16 hi = f2bf(v), lo = f2bf(v - bf2f(hi));
        int frag = ((g >> 4) * KTX + (k >> 5)) * 2;
        int pos = ((g & 15) | (((k >> 3) & 3) << 4)) * 8 + (k & 7);
        xwpk[frag * 512 + pos] = hi;
        xwpk[(frag + 1) * 512 + pos] = lo;
    } else if (idx < N1 + N2 + Gsz) {
        int g = idx - N1 - N2;
        bc[g] = kb[g] + rb[g];
        wt[g] = kW[g * (Dsz + 1) + Dsz] + rW[g * (Hsz + 1) + Hsz];
    }
}

// pack x into per-t fragment layout (hi/lo split)
__global__ __launch_bounds__(256) void pack_x(const float* __restrict__ x,
                                              u16* __restrict__ xpk) {
    int idx = blockIdx.x * 256 + threadIdx.x;   // [0, 2^24)
    int k = idx & 255, b = (idx >> 8) & 511, t = idx >> 17;
    float v = x[((size_t)b * Tsz + t) * Dsz + k];
    u16 hi = f2bf(v), lo = f2bf(v - bf2f(hi));
    size_t frag = (((size_t)t * 32 + (b >> 4)) * KTX + (k >> 5)) * 2;
    int pos = ((b & 15) | (((k >> 3) & 3) << 4)) * 8 + (k & 7);
    xpk[frag * 512 + pos] = hi;
    xpk[(frag + 1) * 512 + pos] = lo;
}

__global__ __launch_bounds__(256) void pack_cw(const float* __restrict__ cW,
                                               u16* __restrict__ cpk) {
    int idx = blockIdx.x * 256 + threadIdx.x;
    if (idx >= Hsz * KC) return;
    int o = idx / KC, k = idx % KC;
    size_t frag = (size_t)(o >> 4) * KTC + (k >> 5);
    int pos = ((o & 15) | (((k >> 3) & 3) << 4)) * 8 + (k & 7);
    cpk[frag * 512 + pos] = f2bf(cW[idx]);
}

// mode 0: bid<196 HW(t) | bid<392 XW(t+1) | bid<776 CONV(t-1)
// mode 1: grid=196, XW only for t (dst = xw buf 0)
// mode 2: grid=384, CONV only (current apk)
__global__ __launch_bounds__(256) void fused_gemm(const u16* __restrict__ xpk,
                                                  const u16* __restrict__ wpk,
                                                  const u16* __restrict__ xwpk,
                                                  const u16* __restrict__ hpk,
                                                  const u16* __restrict__ apk,
                                                  const u16* __restrict__ cpk,
                                                  float* __restrict__ xw,
                                                  float* __restrict__ hw,
                                                  float* __restrict__ cp,
                                                  int t, int mode) {
    int bid = blockIdx.x;
    int lane = threadIdx.x & 63;
    int wave = threadIdx.x >> 6;
    int l15 = lane & 15;
    int lk = lane >> 4;

    int part = 0;   // 0=HW, 1=XW, 2=CONV
    if (mode == 0) {
        if (bid < 196) part = 0;
        else if (bid < 392) { part = 1; bid -= 196; if (t + 1 >= Tsz) return; }
        else { part = 2; bid -= 392; if (t == 0) return; }
    } else if (mode == 1) part = 1;
    else part = 2;

    if (part != 2) {
        int mb = bid & 3, nb = bid >> 2;
        int mbase = mb * 128 + wave * 32;
        int nbase = nb * 32;
        int mt0 = mbase >> 4, nt0 = nbase >> 4;
        f32x4 acc[2][2] = {};
        const u16* Asrc;
        const u16* Bsrc;
        int nkt;
        float* dst;
        if (part == 0) {
            Asrc = hpk; Bsrc = wpk; nkt = KTH; dst = hw;
        } else {
            int t_x = (mode == 1) ? t : t + 1;
            Asrc = xpk + (size_t)t_x * 32 * KTX * 2 * 512;
            Bsrc = xwpk; nkt = KTX;
            dst = xw + (size_t)((mode == 1) ? 0 : ((t + 1) & 1)) * Bsz * Gp;
        }
        for (int kt = 0; kt < nkt; ++kt) {
            bf16x8 ah[2], al[2], bh[2], bl[2];
            #pragma unroll
            for (int mi = 0; mi < 2; ++mi) {
                size_t fb = ((size_t)(mt0 + mi) * nkt + kt) * 2 * 512 + lane * 8;
                ah[mi] = *(const bf16x8*)(Asrc + fb);
                al[mi] = *(const bf16x8*)(Asrc + fb + 512);
            }
            #pragma unroll
            for (int ni = 0; ni < 2; ++ni) {
                size_t fb = ((size_t)(nt0 + ni) * nkt + kt) * 2 * 512 + lane * 8;
                bh[ni] = *(const bf16x8*)(Bsrc + fb);
                bl[ni] = *(const bf16x8*)(Bsrc + fb + 512);
            }
            #pragma unroll
            for (int mi = 0; mi < 2; ++mi)
            #pragma unroll
            for (int ni = 0; ni < 2; ++ni) {
                acc[mi][ni] = __builtin_amdgcn_mfma_f32_16x16x32_bf16(ah[mi], bh[ni], acc[mi][ni], 0, 0, 0);
                acc[mi][ni] = __builtin_amdgcn_mfma_f32_16x16x32_bf16(ah[mi], bl[ni], acc[mi][ni], 0, 0, 0);
                acc[mi][ni] = __builtin_amdgcn_mfma_f32_16x16x32_bf16(al[mi], bh[ni], acc[mi][ni], 0, 0, 0);
            }
        }
        #pragma unroll
        for (int mi = 0; mi < 2; ++mi)
        #pragma unroll
        for (int ni = 0; ni < 2; ++ni) {
            int col = nbase + ni * 16 + l15;
            #pragma unroll
            for (int j = 0; j < 4; ++j) {
                int row = mbase + mi * 16 + lk * 4 + j;
                dst[(size_t)row * Gp + col] = acc[mi][ni][j];
            }
        }
    } else {
        int mb = bid & 3, nb = (bid >> 2) % 12, kz = bid / 48;
        int mbase = mb * 128 + wave * 32;
        int nbase = nb * 32;
        int mt0 = mbase >> 4, nt0 = nbase >> 4;
        f32x4 acc[2][2] = {};
        int kt0 = kz * CITER;
        for (int ki = 0; ki < CITER; ++ki) {
            int kt = kt0 + ki;
            bf16x8 a[2], b[2];
            #pragma unroll
            for (int mi = 0; mi < 2; ++mi)
                a[mi] = *(const bf16x8*)(apk + ((size_t)(mt0 + mi) * KTC + kt) * 512 + lane * 8);
            #pragma unroll
            for (int ni = 0; ni < 2; ++ni)
                b[ni] = *(const bf16x8*)(cpk + ((size_t)(nt0 + ni) * KTC + kt) * 512 + lane * 8);
            #pragma unroll
            for (int mi = 0; mi < 2; ++mi)
            #pragma unroll
            for (int ni = 0; ni < 2; ++ni)
                acc[mi][ni] = __builtin_amdgcn_mfma_f32_16x16x32_bf16(a[mi], b[ni], acc[mi][ni], 0, 0, 0);
        }
        float* outp = cp + (size_t)kz * Bsz * Hsz;
        #pragma unroll
        for (int mi = 0; mi < 2; ++mi)
        #pragma unroll
        for (int ni = 0; ni < 2; ++ni) {
            int col = nbase + ni * 16 + l15;
            #pragma unroll
            for (int j = 0; j < 4; ++j) {
                int row = mbase + mi * 16 + lk * 4 + j;
                outp[(size_t)row * Hsz + col] = acc[mi][ni][j];
            }
        }
    }
}

// one block per batch row; 384 threads. Also finishes step t-1's output.
__global__ __launch_bounds__(384) void cell(const float* __restrict__ xw,
                                            const float* __restrict__ hw,
                                            const float* __restrict__ bc,
                                            const float* __restrict__ wt,
                                            const float* __restrict__ tme,
                                            float* __restrict__ hf,
                                            float* __restrict__ cf,
                                            u16* __restrict__ hpk,
                                            u16* __restrict__ bufh,
                                            float* __restrict__ bufd,
                                            const float* __restrict__ sW,
                                            const float* __restrict__ sb,
                                            const float* __restrict__ rsW,
                                            const float* __restrict__ rsb,
                                            u16* __restrict__ apk,
                                            float* theme,
                                            float* __restrict__ dist_out,
                                            const float* __restrict__ cp,
                                            const float* __restrict__ cb,
                                            float* __restrict__ out_seq, int t) {
    __shared__ float s_fm[Lsz], s_im[Lsz];
    __shared__ float s_hn[Hsz], s_thm[Hsz];
    __shared__ float s_ld[CSs];
    __shared__ float s_th1[HSz];
    __shared__ float s_part[6][HSz];
    __shared__ float s_cd;

    int b = blockIdx.x;
    int tid = threadIdx.x;
    const float* x0 = xw + (size_t)(t & 1) * Bsz * Gp + (size_t)b * Gp;
    const float* x1 = hw + (size_t)b * Gp;
    float tv = tme[b * Tsz + t];

    // ---- merged epilogue for step t-1 ----
    if (t > 0) {
        float convv = cb[tid];
        #pragma unroll
        for (int z = 0; z < CKZ; ++z)
            convv += cp[((size_t)z * Bsz + b) * Hsz + tid];
        float val = theme[(size_t)b * Hsz + tid] * convv + hf[(size_t)b * Hsz + tid];
        out_seq[((size_t)b * Tsz + (t - 1)) * Hsz + tid] = val;
    }

    if (tid == 0) {
        float z0 = x0[0] + x1[0] + bc[0] + tv * wt[0];
        float z1 = x0[1] + x1[1] + bc[1] + tv * wt[1];
        float z2 = x0[2] + x1[2] + bc[2] + tv * wt[2];
        float m = fmaxf(z0, fmaxf(z1, z2));
        float e0 = expf(z0 - m), e1 = expf(z1 - m), e2 = expf(z2 - m);
        float inv = 1.f / (e0 + e1 + e2);
        float p0 = e0 * inv, p1 = e1 * inv;
        s_fm[0] = p0; s_fm[1] = p0 + p1; s_fm[2] = 1.f;
        float w0 = x0[3] + x1[3] + bc[3] + tv * wt[3];
        float w1 = x0[4] + x1[4] + bc[4] + tv * wt[4];
        float w2 = x0[5] + x1[5] + bc[5] + tv * wt[5];
        float mw = fmaxf(w0, fmaxf(w1, w2));
        float f0 = expf(w0 - mw), f1 = expf(w1 - mw), f2 = expf(w2 - mw);
        float invw = 1.f / (f0 + f1 + f2);
        float q1 = f1 * invw, q2 = f2 * invw;
        s_im[0] = 1.f; s_im[1] = q1 + q2; s_im[2] = q2;
        float cd = 1.f - (s_fm[0] + s_fm[1] + s_fm[2]) * (1.f / 3.f);
        s_cd = cd;
        bufd[(t % CSs) * Bsz + b] = cd;
        dist_out[(size_t)t * Bsz + b] = cd;
    }
    __syncthreads();

    int mt = b >> 4, l15b = b & 15;
    {   // gates + cell update
        int l = tid >> 7;
        float fm = s_fm[l], im = s_im[l];
        int g0 = 2 * Lsz + tid;
        float fg = sigm(x0[g0] + x1[g0] + bc[g0] + tv * wt[g0]);
        int g1 = g0 + Hsz, g2 = g0 + 2 * Hsz, g3 = g0 + 3 * Hsz;
        float ig = sigm(x0[g1] + x1[g1] + bc[g1] + tv * wt[g1]);
        float og = sigm(x0[g2] + x1[g2] + bc[g2] + tv * wt[g2]);
        float ci = tanhf(x0[g3] + x1[g3] + bc[g3] + tv * wt[g3]);
        float cl = cf[(size_t)b * Hsz + tid];
        float ov = fm * im;
        float cn = ov * (fg * cl + ig * ci) + (fm - ov) * cl + (im - ov) * ci;
        float hn = og * tanhf(cn);
        cf[(size_t)b * Hsz + tid] = cn;
        hf[(size_t)b * Hsz + tid] = hn;
        u16 hh = f2bf(hn);
        u16 hl = f2bf(hn - bf2f(hh));
        int kt = tid >> 5;
        int pos = (l15b | (((tid >> 3) & 3) << 4)) * 8 + (tid & 7);
        size_t fb = ((size_t)mt * KTH + kt) * 2 * 512;
        hpk[fb + pos] = hh;
        hpk[fb + 512 + pos] = hl;
        s_hn[tid] = hn;
        bufh[((size_t)(t % CSs) * Bsz + b) * Hsz + tid] = hh;
    }
    __syncthreads();

    if (tid == 0) {
        float vals[CSs];
        float cum = 0.f;
        #pragma unroll
        for (int j = 0; j < CSs; ++j) {
            int slot = (t + 1 + j) % CSs;
            float d = (j == CSs - 1) ? s_cd : bufd[slot * Bsz + b];
            cum += d;
            vals[j] = cum;
        }
        float mx = vals[0];
        #pragma unroll
        for (int j = 1; j < CSs; ++j) mx = fmaxf(mx, vals[j]);
        float sum = 0.f;
        #pragma unroll
        for (int j = 0; j < CSs; ++j) { vals[j] = expf(vals[j] - mx); sum += vals[j]; }
        float invs = 1.f / sum;
        #pragma unroll
        for (int j = 0; j < CSs; ++j) s_ld[j] = vals[j] * invs;
    }
    __syncthreads();

    {   // aconv row (packed bf16) + theme-mean
        float acc = 0.f;
        #pragma unroll
        for (int j = 0; j < CSs; ++j) {
            int slot = (t + 1 + j) % CSs;
            float v = (j == CSs - 1) ? s_hn[tid]
                                     : bf2f(bufh[((size_t)slot * Bsz + b) * Hsz + tid]);
            float av = v * s_ld[j];
            int k = tid * CSs + j;
            int kt = k >> 5;
            int pos = (l15b | (((k >> 3) & 3) << 4)) * 8 + (k & 7);
            apk[((size_t)mt * KTC + kt) * 512 + pos] = f2bf(av);
            acc += av;
        }
        s_thm[tid] = acc * 0.1f;
    }
    __syncthreads();

    {   // theme MLP stage 1
        int hs = tid & 63, ck = tid >> 6;
        const float* swr = sW + (size_t)hs * Hsz + ck * 64;
        const float* tm = s_thm + ck * 64;
        float p = 0.f;
        #pragma unroll
        for (int i = 0; i < 64; ++i) p += tm[i] * swr[i];
        s_part[ck][hs] = p;
    }
    __syncthreads();
    if (tid < HSz) {
        float v = sb[tid];
        #pragma unroll
        for (int ck = 0; ck < 6; ++ck) v += s_part[ck][tid];
        s_th1[tid] = fmaxf(v, 0.f);
    }
    __syncthreads();
    {   // theme MLP stage 2
        const float* rr = rsW + (size_t)tid * HSz;
        float v = rsb[tid];
        #pragma unroll
        for (int hs = 0; hs < HSz; ++hs) v += s_th1[hs] * rr[hs];
        theme[(size_t)b * Hsz + tid] = sigm(v);
    }
}

__global__ __launch_bounds__(256) void epi_last(const float* __restrict__ cp,
                                                const float* __restrict__ theme,
                                                const float* __restrict__ h,
                                                const float* __restrict__ cb,
                                                float* __restrict__ out_seq,
                                                float* __restrict__ out_last) {
    int idx = blockIdx.x * 256 + threadIdx.x;
    if (idx >= Bsz * Hsz) return;
    int b = idx / Hsz, o = idx % Hsz;
    float convv = cb[o];
    #pragma unroll
    for (int z = 0; z < CKZ; ++z) convv += cp[(size_t)z * Bsz * Hsz + idx];
    float val = theme[idx] * convv + h[idx];
    out_seq[((size_t)b * Tsz + (Tsz - 1)) * Hsz + o] = val;
    out_last[idx] = val;
}

extern "C" void kernel_launch(void* const* d_in, const int* in_sizes, int n_in,
                              void* d_out, int out_size, void* d_ws, size_t ws_size,
                              hipStream_t stream) {
    const float* x   = (const float*)d_in[0];
    const float* tme = (const float*)d_in[1];
    const float* kW  = (const float*)d_in[2];
    const float* kb  = (const float*)d_in[3];
    const float* rW  = (const float*)d_in[4];
    const float* rb  = (const float*)d_in[5];
    const float* sW  = (const float*)d_in[6];
    const float* sb  = (const float*)d_in[7];
    const float* rsW = (const float*)d_in[8];
    const float* rsb = (const float*)d_in[9];
    const float* cW  = (const float*)d_in[10];
    const float* cb  = (const float*)d_in[11];

    char* ws = (char*)d_ws;
    u16*   hpk  = (u16*)(ws + O_HPK);
    float* cf   = (float*)(ws + O_CF);
    u16*   bufh = (u16*)(ws + O_BUFH);
    float* bufd = (float*)(ws + O_BUFD);
    u16*   wpk  = (u16*)(ws + O_WPK);
    u16*   xwpk = (u16*)(ws + O_XWPK);
    u16*   cpk  = (u16*)(ws + O_CPK);
    float* bc   = (float*)(ws + O_BC);
    float* wt   = (float*)(ws + O_WT);
    float* xwb  = (float*)(ws + O_XW);
    float* hwb  = (float*)(ws + O_HW);
    float* cp   = (float*)(ws + O_CP);
    u16*   apk  = (u16*)(ws + O_APK);
    float* thm  = (float*)(ws + O_THM);
    float* hf   = (float*)(ws + O_HF);
    u16*   xpk  = (u16*)(ws + O_XPK);

    float* out_last = (float*)d_out;
    float* out_seq  = out_last + (size_t)Bsz * Hsz;
    float* out_dist = out_seq + (size_t)Bsz * Tsz * Hsz;

    zero4<<<(int)(ZERO_END / 16 + 255) / 256, 256, 0, stream>>>((float4*)ws, (int)(ZERO_END / 16));
    {
        int nW = Gp * KH + Gp * KX + Gsz;
        build_w<<<(nW + 255) / 256, 256, 0, stream>>>(kW, kb, rW, rb, wpk, xwpk, bc, wt);
    }
    pack_x<<<(Tsz * Bsz * KX) / 256, 256, 0, stream>>>(x, xpk);
    pack_cw<<<(Hsz * KC + 255) / 256, 256, 0, stream>>>(cW, cpk);
    // xw(0) into buffer 0
    fused_gemm<<<196, 256, 0, stream>>>(xpk, wpk, xwpk, hpk, apk, cpk,
                                        xwb, hwb, cp, 0, 1);

    for (int t = 0; t < Tsz; ++t) {
        fused_gemm<<<776, 256, 0, stream>>>(xpk, wpk, xwpk, hpk, apk, cpk,
                                            xwb, hwb, cp, t, 0);
        cell<<<Bsz, 384, 0, stream>>>(xwb, hwb, bc, wt, tme, hf, cf, hpk,
                                      bufh, bufd, sW, sb, rsW, rsb, apk, thm,
                                      out_dist, cp, cb, out_seq, t);
    }
    // conv for t=127 + final epilogue
    fused_gemm<<<384, 256, 0, stream>>>(xpk, wpk, xwpk, hpk, apk, cpk,
                                        xwb, hwb, cp, Tsz, 2);
    epi_last<<<(Bsz * Hsz + 255) / 256, 256, 0, stream>>>(cp, thm, hf, cb, out_seq, out_last);
}